// Round 3
// baseline (1092.742 us; speedup 1.0000x reference)
//
#include <hip/hip_runtime.h>
#include <hip/hip_bf16.h>
#include <math.h>

#define NPTS 4096
#define KD   64
#define BR   128                      // rows per block
#define BC   128                      // cols per tile
#define NSPLIT 4                      // column splits (partial LSE per split)
#define CT   (NPTS / (BC * NSPLIT))   // 8 col tiles per block
#define LDB  68                       // bf16 elems per LDS row: 136 B stride ->
                                      // bank = 2*ln mod 32 -> 2-way (free) b64 reads
#define NTHREADS 256
#define BLOG  (-8.317766166719343f)   // -ln(4096)
#define LOG2E 1.4426950408889634f
#define LN2   0.6931471805599453f

typedef __bf16 bf16x8 __attribute__((ext_vector_type(8)));
typedef float  f32x16 __attribute__((ext_vector_type(16)));

struct FusedArgs {
  const unsigned short* X[4];   // bf16 row-major [NPTS][KD]
  const unsigned short* Y[4];
  const float* q;               // [4][NPTS] base-2 col logit offsets
  float* pm;                    // [4][NSPLIT][NPTS] partial max (base-2)
  float* ps;                    // [4][NSPLIT][NPTS] partial sum (base-2)
  float ie2;                    // (1/eps) * log2(e)
};

struct MergeArgs {
  const float* pm;
  const float* ps;
  const float* XSQ[4];   // 0.5*|x_i|^2 of the row point set
  const float* fprev[4]; // nullable
  float* fout[4];
  float* qout;           // [4][NPTS] base-2 q for the NEXT pass
  float eps;
  float alpha;
  float beta;
  float inv_eps_next;
};

// One softmin pass for all 4 directions (blockIdx.z), column-split partials.
// logit2_ij = q2_j + dot(x_i,y_j)*ie2 ; f_i finalized in merge.
// Dot products via bf16 MFMA 32x32x16; online softmax base-2 in fp32.
__global__ __launch_bounds__(NTHREADS, 2)
void fused_softmin(FusedArgs A) {
  __shared__ __align__(16) __bf16 YT[2][BC * LDB];

  const int tid  = threadIdx.x;
  const int lane = tid & 63;
  const int wave = tid >> 6;
  const int hh   = lane >> 5;   // k-half for A/B frags; row-offset bit for C
  const int ln   = lane & 31;   // row (A) / col (B,C) within 32
  const int rowblk = blockIdx.x;
  const int split  = blockIdx.y;
  const int dir    = blockIdx.z;

  const __bf16* __restrict__ Xb = (const __bf16*)A.X[dir];
  const __bf16* __restrict__ Yb = (const __bf16*)A.Y[dir];
  const float* __restrict__ qg  = A.q + dir * NPTS;
  const float ie2 = A.ie2;
  const int row0 = rowblk * BR;
  const int col0 = split * (CT * BC);

  // A fragments: direct global -> VGPR, once.
  bf16x8 af[4];
  {
    const __bf16* ap = Xb + (size_t)(row0 + wave * 32 + ln) * KD + hh * 8;
#pragma unroll
    for (int ks = 0; ks < 4; ++ks) {
      union { uint4 u; bf16x8 v; } t;
      t.u = *(const uint4*)(ap + ks * 16);
      af[ks] = t.v;
    }
  }

  // stage tile 0 into buffer 0
#pragma unroll
  for (int it = 0; it < 4; ++it) {
    int idx = it * NTHREADS + tid;      // 0..1023
    int r  = idx >> 3;                  // 0..127
    int sg = idx & 7;                   // 16B segment along K
    uint4 v = *(const uint4*)(Yb + (size_t)(col0 + r) * KD + sg * 8);
    __bf16* d = &YT[0][r * LDB + sg * 8];
    *(uint2*)(d)     = make_uint2(v.x, v.y);
    *(uint2*)(d + 4) = make_uint2(v.z, v.w);
  }
  __syncthreads();

  float m[16], s[16];
#pragma unroll
  for (int r = 0; r < 16; ++r) { m[r] = -__builtin_inff(); s[r] = 0.f; }

  for (int tile = 0; tile < CT; ++tile) {
    const int cb = tile & 1;

    // prefetch next tile into registers (lands during K-loop + epilogue)
    uint4 stg[4];
    if (tile < CT - 1) {
      const int nc0 = col0 + (tile + 1) * BC;
#pragma unroll
      for (int it = 0; it < 4; ++it) {
        int idx = it * NTHREADS + tid;
        int r = idx >> 3, sg = idx & 7;
        stg[it] = *(const uint4*)(Yb + (size_t)(nc0 + r) * KD + sg * 8);
      }
    }

    float qv[4];
    const int c0 = col0 + tile * BC;
#pragma unroll
    for (int t = 0; t < 4; ++t) qv[t] = qg[c0 + t * 32 + ln];

    f32x16 acc[4];
#pragma unroll
    for (int t = 0; t < 4; ++t)
#pragma unroll
      for (int i = 0; i < 16; ++i) acc[t][i] = 0.f;

    const __bf16* yp = &YT[cb][ln * LDB + hh * 8];
#pragma unroll
    for (int ks = 0; ks < 4; ++ks) {
#pragma unroll
      for (int t = 0; t < 4; ++t) {
        union { uint2 u[2]; bf16x8 v; } b;
        const __bf16* p = yp + t * 32 * LDB + ks * 16;
        b.u[0] = *(const uint2*)(p);
        b.u[1] = *(const uint2*)(p + 4);
        acc[t] = __builtin_amdgcn_mfma_f32_32x32x16_bf16(af[ks], b.v, acc[t], 0, 0, 0);
      }
    }

#pragma unroll
    for (int r = 0; r < 16; ++r) {
      float l0 = fmaf(acc[0][r], ie2, qv[0]);
      float l1 = fmaf(acc[1][r], ie2, qv[1]);
      float l2 = fmaf(acc[2][r], ie2, qv[2]);
      float l3 = fmaf(acc[3][r], ie2, qv[3]);
      float tmax = fmaxf(fmaxf(l0, l1), fmaxf(l2, l3));
      float mn = fmaxf(m[r], tmax);
      float sadd = exp2f(l0 - mn) + exp2f(l1 - mn) +
                   exp2f(l2 - mn) + exp2f(l3 - mn);
      s[r] = fmaf(s[r], exp2f(m[r] - mn), sadd);
      m[r] = mn;
    }

    if (tile < CT - 1) {
      const int nb = cb ^ 1;
#pragma unroll
      for (int it = 0; it < 4; ++it) {
        int idx = it * NTHREADS + tid;
        int r = idx >> 3, sg = idx & 7;
        __bf16* d = &YT[nb][r * LDB + sg * 8];
        *(uint2*)(d)     = make_uint2(stg[it].x, stg[it].y);
        *(uint2*)(d + 4) = make_uint2(stg[it].z, stg[it].w);
      }
    }
    __syncthreads();
  }

  // cross-lane merge over the 32 column-owner lanes (xor masks 1..16 keep hh)
#pragma unroll
  for (int r = 0; r < 16; ++r) {
#pragma unroll
    for (int d = 1; d < 32; d <<= 1) {
      float mo = __shfl_xor(m[r], d, 64);
      float so = __shfl_xor(s[r], d, 64);
      float mn = fmaxf(m[r], mo);
      s[r] = exp2f(m[r] - mn) * s[r] + exp2f(mo - mn) * so;
      m[r] = mn;
    }
  }
  if (ln == 0) {
#pragma unroll
    for (int r = 0; r < 16; ++r) {
      int row = row0 + wave * 32 + (r & 3) + ((r >> 2) << 3) + (hh << 2);
      size_t gi = (size_t)(dir * NSPLIT + split) * NPTS + row;
      A.pm[gi] = m[r];
      A.ps[gi] = s[r];
    }
  }
}

// Combine NSPLIT partials -> f value; blend alpha*prev + beta*v; emit q2 for
// the next pass. This thread's (dir,row) is column `row` of direction
// pair(dir) = {1,0,2,3}[dir], whose column sqnorms are XSQ[dir].
__global__ void merge_softmin(MergeArgs A) {
  int gid = blockIdx.x * blockDim.x + threadIdx.x;  // 0..16383
  int dir = gid >> 12;
  int row = gid & (NPTS - 1);
  float ms[NSPLIT], ss[NSPLIT];
  float m = -__builtin_inff();
#pragma unroll
  for (int sp = 0; sp < NSPLIT; ++sp) {
    ms[sp] = A.pm[(size_t)(dir * NSPLIT + sp) * NPTS + row];
    ss[sp] = A.ps[(size_t)(dir * NSPLIT + sp) * NPTS + row];
    m = fmaxf(m, ms[sp]);
  }
  float s = 0.f;
#pragma unroll
  for (int sp = 0; sp < NSPLIT; ++sp) s += ss[sp] * exp2f(ms[sp] - m);
  float lse_e = LN2 * (m + log2f(s));
  float xsq = A.XSQ[dir][row];
  float v = xsq - A.eps * lse_e;
  float prev = A.fprev[dir] ? A.fprev[dir][row] : 0.0f;
  float f = A.alpha * prev + A.beta * v;
  A.fout[dir][row] = f;
  const int qpair[4] = {1, 0, 2, 3};
  A.qout[qpair[dir] * NPTS + row] =
      (BLOG + (f - xsq) * A.inv_eps_next) * LOG2E;
}

// sqnorms + bf16 conversion + initial q (h = blog at eps0)
__global__ void prep(const float* __restrict__ x, const float* __restrict__ y,
                     float* xs, float* ys,
                     unsigned short* xb, unsigned short* yb,
                     float* q, float inv_eps0) {
  int gid = blockIdx.x * blockDim.x + threadIdx.x;  // 0..8191
  int isx = (gid < NPTS) ? 1 : 0;
  const float* p = isx ? x : y;
  int row = gid & (NPTS - 1);
  const float4* r4 = (const float4*)(p + (size_t)row * KD);
  unsigned short* ob = (isx ? xb : yb) + (size_t)row * KD;
  float s = 0.f;
#pragma unroll
  for (int i = 0; i < 16; ++i) {
    float4 v = r4[i];
    s += v.x * v.x + v.y * v.y + v.z * v.z + v.w * v.w;
    union { __bf16 h[4]; uint2 u; } t;
    t.h[0] = (__bf16)v.x; t.h[1] = (__bf16)v.y;
    t.h[2] = (__bf16)v.z; t.h[3] = (__bf16)v.w;
    *(uint2*)(ob + i * 4) = t.u;
  }
  float half_sq = 0.5f * s;
  (isx ? xs : ys)[row] = half_sq;
  float q0 = (BLOG - half_sq * inv_eps0) * LOG2E;
  if (isx) { q[1 * NPTS + row] = q0; q[2 * NPTS + row] = q0; }
  else     { q[0 * NPTS + row] = q0; q[3 * NPTS + row] = q0; }
}

__global__ void final_reduce(const float* __restrict__ fba, const float* __restrict__ gab,
                             const float* __restrict__ faa, const float* __restrict__ gbb,
                             float* out) {
  __shared__ float red[256];
  int t = threadIdx.x;
  float s = 0.f;
  for (int i = t; i < NPTS; i += 256)
    s += (fba[i] - faa[i]) + (gab[i] - gbb[i]);
  red[t] = s;
  __syncthreads();
  for (int off = 128; off > 0; off >>= 1) {
    if (t < off) red[t] += red[t + off];
    __syncthreads();
  }
  if (t == 0) out[0] = red[0] * (1.0f / NPTS);
}

extern "C" void kernel_launch(void* const* d_in, const int* in_sizes, int n_in,
                              void* d_out, int out_size, void* d_ws, size_t ws_size,
                              hipStream_t stream) {
  const float* x = (const float*)d_in[0];
  const float* y = (const float*)d_in[1];
  float* out = (float*)d_out;
  float* w = (float*)d_ws;

  // ws layout (float slots); total ~467K floats = 1.87 MB (d_ws is ~256 MB)
  float* xs_x = w;                        // [NPTS]
  float* xs_y = w + NPTS;                 // [NPTS]
  float* potA = w + 2 * NPTS;             // [4][NPTS]
  float* potB = w + 6 * NPTS;             // [4][NPTS]
  float* fn   = w + 10 * NPTS;            // [4][NPTS]
  float* pm   = w + 14 * NPTS;            // [4][NSPLIT][NPTS]
  float* ps   = w + 30 * NPTS;            // [4][NSPLIT][NPTS]
  float* q    = w + 46 * NPTS;            // [4][NPTS]
  unsigned short* xb = (unsigned short*)(w + 50 * NPTS);  // [NPTS][KD] bf16
  unsigned short* yb = (unsigned short*)(w + 82 * NPTS);  // [NPTS][KD] bf16

  // geomloss epsilon_schedule(p=2, diameter=20, blur=0.01, scaling=0.7)
  double eps_list[32];
  int neps = 0;
  {
    double start = 2.0 * log(20.0);
    double stop  = 2.0 * log(0.01);
    double step  = 2.0 * log(0.7);
    eps_list[neps++] = 400.0;
    int cnt = (int)ceil((stop - start) / step);  // 22
    for (int i = 0; i < cnt && neps < 30; ++i) eps_list[neps++] = exp(start + (double)i * step);
    eps_list[neps++] = 1e-4;                     // neps == 24
  }

  // dir 0: ft  (rows x, cols y) ; dir 1: gt (rows y, cols x)
  // dir 2: f_aa (x,x)           ; dir 3: g_bb (y,y)
  const unsigned short* Xd[4] = {xb, yb, xb, yb};
  const unsigned short* Yd[4] = {yb, xb, xb, yb};
  const float* XSQd[4] = {xs_x, xs_y, xs_x, xs_y};

  float* PA[4] = {potA, potA + NPTS, potA + 2 * NPTS, potA + 3 * NPTS};
  float* PB[4] = {potB, potB + NPTS, potB + 2 * NPTS, potB + 3 * NPTS};
  float* FN[4] = {fn, fn + NPTS, fn + 2 * NPTS, fn + 3 * NPTS};

  prep<<<dim3(32), dim3(256), 0, stream>>>(x, y, xs_x, xs_y, xb, yb, q,
                                           (float)(1.0 / eps_list[0]));

  dim3 fgrid(NPTS / BR, NSPLIT, 4);

  auto pass = [&](double eps_d, double eps_next, const float* const* fprev,
                  float* const* fout, float alpha, float beta) {
    float ef = (float)eps_d;
    FusedArgs fa;
    for (int d = 0; d < 4; ++d) { fa.X[d] = Xd[d]; fa.Y[d] = Yd[d]; }
    fa.q = q; fa.pm = pm; fa.ps = ps;
    fa.ie2 = (float)(LOG2E / eps_d);
    fused_softmin<<<fgrid, dim3(NTHREADS), 0, stream>>>(fa);

    MergeArgs ma;
    for (int d = 0; d < 4; ++d) {
      ma.XSQ[d] = XSQd[d];
      ma.fprev[d] = fprev ? fprev[d] : nullptr;
      ma.fout[d] = fout[d];
    }
    ma.pm = pm; ma.ps = ps; ma.qout = q;
    ma.eps = ef; ma.alpha = alpha; ma.beta = beta;
    ma.inv_eps_next = (float)(1.0 / eps_next);
    merge_softmin<<<dim3(64), dim3(256), 0, stream>>>(ma);
  };

  // init potentials at eps_list[0] (h = blog); q for loop-pass 0 uses eps_list[0]
  pass(eps_list[0], eps_list[0], nullptr, PA, 0.f, 1.f);

  // symmetric Sinkhorn annealing loop with 0.5 averaging
  for (int it = 0; it < neps; ++it) {
    float** R = (it & 1) ? PB : PA;  // read (old) buffers
    float** W = (it & 1) ? PA : PB;  // write (new) buffers
    double eps_next = eps_list[(it + 1 < neps) ? it + 1 : neps - 1];
    pass(eps_list[it], eps_next, (const float* const*)R, W, 0.5f, 0.5f);
  }
  // neps even -> converged potentials live in PA; q now built from PA at eps_last

  // final extrapolation at eps = blur^p
  pass(eps_list[neps - 1], eps_list[neps - 1], nullptr, FN, 0.f, 1.f);

  final_reduce<<<dim3(1), dim3(256), 0, stream>>>(FN[0], FN[1], FN[2], FN[3], out);
}

// Round 4
// 882.998 us; speedup vs baseline: 1.2375x; 1.2375x over previous
//
#include <hip/hip_runtime.h>
#include <hip/hip_bf16.h>
#include <math.h>

#define NPTS 4096
#define KD   64
#define BR   64                       // rows per block (4 waves x 16 rows)
#define BC   128                      // cols per tile
#define NSPLIT 4                      // column splits (partial LSE per split)
#define CT   (NPTS / (BC * NSPLIT))   // 8 col tiles per block
#define NTHREADS 256
#define BLOG  (-8.317766166719343f)   // -ln(4096)
#define LOG2E 1.4426950408889634f
#define LN2   0.6931471805599453f

typedef __bf16 bf16x8 __attribute__((ext_vector_type(8)));
typedef float  f32x4  __attribute__((ext_vector_type(4)));

struct FusedArgs {
  const unsigned short* X[4];   // bf16 row-major [NPTS][KD]
  const unsigned short* Y[4];
  const float* q;               // [4][NPTS] base-2 col logit offsets
  float* pm;                    // [4][NSPLIT][NPTS] partial max (base-2)
  float* ps;                    // [4][NSPLIT][NPTS] partial sum (base-2)
  float ie2;                    // (1/eps) * log2(e)
};

struct MergeArgs {
  const float* pm;
  const float* ps;
  const float* XSQ[4];   // 0.5*|x_i|^2 of the row point set
  const float* fprev[4]; // nullable
  float* fout[4];
  float* qout;           // [4][NPTS] base-2 q for the NEXT pass
  float eps;
  float alpha;
  float beta;
  float inv_eps_next;
};

// async 16B/lane global->LDS; lds dest = wave-uniform base + lane*16 (HW scatter)
__device__ __forceinline__ void gll16(const void* g, void* l) {
  __builtin_amdgcn_global_load_lds(
      (const __attribute__((address_space(1))) void*)g,
      (__attribute__((address_space(3))) void*)l, 16, 0, 0);
}

// One softmin pass for all 4 directions (blockIdx.z), column-split partials.
// logit2_ij = q2_j + dot(x_i,y_j)*ie2 ; f_i finalized in merge.
// MFMA 16x16x32 bf16; Y tile staged via global_load_lds with XOR source
// swizzle: LDS 16B-seg p of col r holds global k-seg (p ^ (r&7)) -> B-frag
// b128 reads are 2-way (free) with NO padding (gll needs lane-linear dest).
__global__ __launch_bounds__(NTHREADS, 4)
void fused_softmin(FusedArgs A) {
  __shared__ __align__(16) __bf16 YT[2][BC * KD];   // 2 x 16 KB
  __shared__ __align__(16) float QL[BC * CT];       // 4 KB: this split's q

  const int tid  = threadIdx.x;
  const int lane = tid & 63;
  const int wave = tid >> 6;
  const int ln16 = lane & 15;   // A row / B,C col within 16
  const int rg   = lane >> 4;   // k-quad for A/B; row-group for C
  const int ln7  = ln16 & 7;
  const int rowblk = blockIdx.x;
  const int split  = blockIdx.y;
  const int dir    = blockIdx.z;

  const __bf16* __restrict__ Xb = (const __bf16*)A.X[dir];
  const __bf16* __restrict__ Yb = (const __bf16*)A.Y[dir];
  const float* __restrict__ qg  = A.q + dir * NPTS;
  const float ie2 = A.ie2;
  const int row0 = rowblk * BR;
  const int col0 = split * (CT * BC);

  // staging geometry (per lane, per issue `it`): linear idx = it*256 + tid
  // row = idx>>3 (0..127), lds seg q = idx&7, global seg = q ^ (row&7)
  const int srow = (tid >> 3);         // + it*32
  const int sseg = (tid & 7);

  // issue tile-0 Y staging + q staging (async), A frags (sync loads)
#pragma unroll
  for (int it = 0; it < 4; ++it) {
    int r = it * 32 + srow;
    gll16(Yb + (size_t)(col0 + r) * KD + ((sseg ^ (r & 7)) << 3),
          (__bf16*)YT[0] + it * 2048 + wave * 512);
  }
  gll16(qg + col0 + (tid << 2), QL + wave * 256);

  bf16x8 af[2];
  {
    const __bf16* ap = Xb + (size_t)(row0 + wave * 16 + ln16) * KD + rg * 8;
#pragma unroll
    for (int ks = 0; ks < 2; ++ks) {
      union { uint4 u; bf16x8 v; } t;
      t.u = *(const uint4*)(ap + ks * 32);
      af[ks] = t.v;
    }
  }

  float m[4], s[4];
#pragma unroll
  for (int r = 0; r < 4; ++r) { m[r] = -__builtin_inff(); s[r] = 0.f; }

  __syncthreads();   // drains tile-0 + q staging

  for (int tile = 0; tile < CT; ++tile) {
    const int cb = tile & 1;

    // async prefetch next tile into the other buffer (drained by the
    // end-of-tile barrier, after a full tile of compute)
    if (tile < CT - 1) {
      const int nc0 = col0 + (tile + 1) * BC;
      __bf16* dst = (__bf16*)YT[cb ^ 1] + wave * 512;
#pragma unroll
      for (int it = 0; it < 4; ++it) {
        int r = it * 32 + srow;
        gll16(Yb + (size_t)(nc0 + r) * KD + ((sseg ^ (r & 7)) << 3),
              dst + it * 2048);
      }
    }

    float qv[8];
#pragma unroll
    for (int t = 0; t < 8; ++t) qv[t] = QL[tile * BC + t * 16 + ln16];

    f32x4 acc[8];
#pragma unroll
    for (int t = 0; t < 8; ++t)
#pragma unroll
      for (int i = 0; i < 4; ++i) acc[t][i] = 0.f;

    const __bf16* ybase = YT[cb] + ln16 * KD;
#pragma unroll
    for (int ks = 0; ks < 2; ++ks) {
      const int p = ((ks << 2) | rg) ^ ln7;
#pragma unroll
      for (int t = 0; t < 8; ++t) {
        union { uint4 u; bf16x8 v; } bb;
        bb.u = *(const uint4*)(ybase + t * 16 * KD + p * 8);
        acc[t] = __builtin_amdgcn_mfma_f32_16x16x32_bf16(af[ks], bb.v, acc[t], 0, 0, 0);
      }
    }

#pragma unroll
    for (int r = 0; r < 4; ++r) {
      float l[8];
#pragma unroll
      for (int t = 0; t < 8; ++t) l[t] = fmaf(acc[t][r], ie2, qv[t]);
      float mn = m[r];
#pragma unroll
      for (int t = 0; t < 8; ++t) mn = fmaxf(mn, l[t]);
      float sadd = 0.f;
#pragma unroll
      for (int t = 0; t < 8; ++t) sadd += exp2f(l[t] - mn);
      s[r] = fmaf(s[r], exp2f(m[r] - mn), sadd);
      m[r] = mn;
    }
    __syncthreads();
  }

  // cross-lane merge over the 16 column-owner lanes (masks 1..8 keep rg)
#pragma unroll
  for (int r = 0; r < 4; ++r) {
#pragma unroll
    for (int d = 1; d < 16; d <<= 1) {
      float mo = __shfl_xor(m[r], d, 64);
      float so = __shfl_xor(s[r], d, 64);
      float mn = fmaxf(m[r], mo);
      s[r] = exp2f(m[r] - mn) * s[r] + exp2f(mo - mn) * so;
      m[r] = mn;
    }
  }
  if (ln16 == 0) {
#pragma unroll
    for (int r = 0; r < 4; ++r) {
      int row = row0 + wave * 16 + rg * 4 + r;
      size_t gi = (size_t)(dir * NSPLIT + split) * NPTS + row;
      A.pm[gi] = m[r];
      A.ps[gi] = s[r];
    }
  }
}

// Combine NSPLIT partials -> f value; blend alpha*prev + beta*v; emit q2 for
// the next pass (this row is a column of direction qpair[dir]).
__global__ void merge_softmin(MergeArgs A) {
  int gid = blockIdx.x * blockDim.x + threadIdx.x;  // 0..16383
  int dir = gid >> 12;
  int row = gid & (NPTS - 1);
  float ms[NSPLIT], ss[NSPLIT];
  float m = -__builtin_inff();
#pragma unroll
  for (int sp = 0; sp < NSPLIT; ++sp) {
    ms[sp] = A.pm[(size_t)(dir * NSPLIT + sp) * NPTS + row];
    ss[sp] = A.ps[(size_t)(dir * NSPLIT + sp) * NPTS + row];
    m = fmaxf(m, ms[sp]);
  }
  float s = 0.f;
#pragma unroll
  for (int sp = 0; sp < NSPLIT; ++sp) s += ss[sp] * exp2f(ms[sp] - m);
  float lse_e = LN2 * (m + log2f(s));
  float xsq = A.XSQ[dir][row];
  float v = xsq - A.eps * lse_e;
  float prev = A.fprev[dir] ? A.fprev[dir][row] : 0.0f;
  float f = A.alpha * prev + A.beta * v;
  A.fout[dir][row] = f;
  const int qpair[4] = {1, 0, 2, 3};
  A.qout[qpair[dir] * NPTS + row] =
      (BLOG + (f - xsq) * A.inv_eps_next) * LOG2E;
}

// sqnorms + bf16 conversion + initial q (h = blog at eps0)
__global__ void prep(const float* __restrict__ x, const float* __restrict__ y,
                     float* xs, float* ys,
                     unsigned short* xb, unsigned short* yb,
                     float* q, float inv_eps0) {
  int gid = blockIdx.x * blockDim.x + threadIdx.x;  // 0..8191
  int isx = (gid < NPTS) ? 1 : 0;
  const float* p = isx ? x : y;
  int row = gid & (NPTS - 1);
  const float4* r4 = (const float4*)(p + (size_t)row * KD);
  unsigned short* ob = (isx ? xb : yb) + (size_t)row * KD;
  float s = 0.f;
#pragma unroll
  for (int i = 0; i < 16; ++i) {
    float4 v = r4[i];
    s += v.x * v.x + v.y * v.y + v.z * v.z + v.w * v.w;
    union { __bf16 h[4]; uint2 u; } t;
    t.h[0] = (__bf16)v.x; t.h[1] = (__bf16)v.y;
    t.h[2] = (__bf16)v.z; t.h[3] = (__bf16)v.w;
    *(uint2*)(ob + i * 4) = t.u;
  }
  float half_sq = 0.5f * s;
  (isx ? xs : ys)[row] = half_sq;
  float q0 = (BLOG - half_sq * inv_eps0) * LOG2E;
  if (isx) { q[1 * NPTS + row] = q0; q[2 * NPTS + row] = q0; }
  else     { q[0 * NPTS + row] = q0; q[3 * NPTS + row] = q0; }
}

__global__ void final_reduce(const float* __restrict__ fba, const float* __restrict__ gab,
                             const float* __restrict__ faa, const float* __restrict__ gbb,
                             float* out) {
  __shared__ float red[256];
  int t = threadIdx.x;
  float s = 0.f;
  for (int i = t; i < NPTS; i += 256)
    s += (fba[i] - faa[i]) + (gab[i] - gbb[i]);
  red[t] = s;
  __syncthreads();
  for (int off = 128; off > 0; off >>= 1) {
    if (t < off) red[t] += red[t + off];
    __syncthreads();
  }
  if (t == 0) out[0] = red[0] * (1.0f / NPTS);
}

extern "C" void kernel_launch(void* const* d_in, const int* in_sizes, int n_in,
                              void* d_out, int out_size, void* d_ws, size_t ws_size,
                              hipStream_t stream) {
  const float* x = (const float*)d_in[0];
  const float* y = (const float*)d_in[1];
  float* out = (float*)d_out;
  float* w = (float*)d_ws;

  // ws layout (float slots); total ~467K floats = 1.87 MB
  float* xs_x = w;                        // [NPTS]
  float* xs_y = w + NPTS;                 // [NPTS]
  float* potA = w + 2 * NPTS;             // [4][NPTS]
  float* potB = w + 6 * NPTS;             // [4][NPTS]
  float* fn   = w + 10 * NPTS;            // [4][NPTS]
  float* pm   = w + 14 * NPTS;            // [4][NSPLIT][NPTS]
  float* ps   = w + 30 * NPTS;            // [4][NSPLIT][NPTS]
  float* q    = w + 46 * NPTS;            // [4][NPTS]
  unsigned short* xb = (unsigned short*)(w + 50 * NPTS);  // [NPTS][KD] bf16
  unsigned short* yb = (unsigned short*)(w + 82 * NPTS);  // [NPTS][KD] bf16

  // geomloss epsilon_schedule(p=2, diameter=20, blur=0.01, scaling=0.7)
  double eps_list[32];
  int neps = 0;
  {
    double start = 2.0 * log(20.0);
    double stop  = 2.0 * log(0.01);
    double step  = 2.0 * log(0.7);
    eps_list[neps++] = 400.0;
    int cnt = (int)ceil((stop - start) / step);  // 22
    for (int i = 0; i < cnt && neps < 30; ++i) eps_list[neps++] = exp(start + (double)i * step);
    eps_list[neps++] = 1e-4;                     // neps == 24
  }

  // dir 0: ft  (rows x, cols y) ; dir 1: gt (rows y, cols x)
  // dir 2: f_aa (x,x)           ; dir 3: g_bb (y,y)
  const unsigned short* Xd[4] = {xb, yb, xb, yb};
  const unsigned short* Yd[4] = {yb, xb, xb, yb};
  const float* XSQd[4] = {xs_x, xs_y, xs_x, xs_y};

  float* PA[4] = {potA, potA + NPTS, potA + 2 * NPTS, potA + 3 * NPTS};
  float* PB[4] = {potB, potB + NPTS, potB + 2 * NPTS, potB + 3 * NPTS};
  float* FN[4] = {fn, fn + NPTS, fn + 2 * NPTS, fn + 3 * NPTS};

  prep<<<dim3(32), dim3(256), 0, stream>>>(x, y, xs_x, xs_y, xb, yb, q,
                                           (float)(1.0 / eps_list[0]));

  dim3 fgrid(NPTS / BR, NSPLIT, 4);   // 64 x 4 x 4 = 1024 blocks = 4/CU

  auto pass = [&](double eps_d, double eps_next, const float* const* fprev,
                  float* const* fout, float alpha, float beta) {
    float ef = (float)eps_d;
    FusedArgs fa;
    for (int d = 0; d < 4; ++d) { fa.X[d] = Xd[d]; fa.Y[d] = Yd[d]; }
    fa.q = q; fa.pm = pm; fa.ps = ps;
    fa.ie2 = (float)(LOG2E / eps_d);
    fused_softmin<<<fgrid, dim3(NTHREADS), 0, stream>>>(fa);

    MergeArgs ma;
    for (int d = 0; d < 4; ++d) {
      ma.XSQ[d] = XSQd[d];
      ma.fprev[d] = fprev ? fprev[d] : nullptr;
      ma.fout[d] = fout[d];
    }
    ma.pm = pm; ma.ps = ps; ma.qout = q;
    ma.eps = ef; ma.alpha = alpha; ma.beta = beta;
    ma.inv_eps_next = (float)(1.0 / eps_next);
    merge_softmin<<<dim3(64), dim3(256), 0, stream>>>(ma);
  };

  // init potentials at eps_list[0] (h = blog); q for loop-pass 0 uses eps_list[0]
  pass(eps_list[0], eps_list[0], nullptr, PA, 0.f, 1.f);

  // symmetric Sinkhorn annealing loop with 0.5 averaging
  for (int it = 0; it < neps; ++it) {
    float** R = (it & 1) ? PB : PA;  // read (old) buffers
    float** W = (it & 1) ? PA : PB;  // write (new) buffers
    double eps_next = eps_list[(it + 1 < neps) ? it + 1 : neps - 1];
    pass(eps_list[it], eps_next, (const float* const*)R, W, 0.5f, 0.5f);
  }
  // neps even -> converged potentials live in PA; q now built from PA at eps_last

  // final extrapolation at eps = blur^p
  pass(eps_list[neps - 1], eps_list[neps - 1], nullptr, FN, 0.f, 1.f);

  final_reduce<<<dim3(1), dim3(256), 0, stream>>>(FN[0], FN[1], FN[2], FN[3], out);
}